// Round 2
// baseline (670.780 us; speedup 1.0000x reference)
//
#include <hip/hip_runtime.h>
#include <float.h>

#define EMBED   64
#define CODES   4096
#define NROWS   65536      // 512*8192/64
#define NELEM   4194304    // 512*8192
#define BR      32         // rows per block
#define CHUNK   128        // codes staged per chunk
#define NCHUNK  (CODES / CHUNK)

// ws layout: [0 .. CODES-1] float c_j = ||e_j||^2 (np-fp32-emulated) ; then one double loss accumulator
__global__ void vq_precompute(const float* __restrict__ E, float* __restrict__ cbuf,
                              double* __restrict__ accum) {
    int j = blockIdx.x * 256 + threadIdx.x;
    // Emulate np.sum(E*E, axis=0) for C-order (64,4096): sequential over i, fp32,
    // square and add as separate rounded ops (no fma contraction).
    float v = E[j];
    float s = __fmul_rn(v, v);
    for (int i = 1; i < EMBED; ++i) {
        v = E[(size_t)i * CODES + j];
        s = __fadd_rn(s, __fmul_rn(v, v));
    }
    cbuf[j] = s;
    if (j == 0) *accum = 0.0;  // d_ws is poisoned 0xAA before every launch
}

__global__ __launch_bounds__(256)
void vq_main(const float* __restrict__ X, const float* __restrict__ E,
             const float* __restrict__ cbuf, double* __restrict__ accum,
             float* __restrict__ out) {
    __shared__ float xs[EMBED][BR];      // x tile, transposed: xs[i][r]   (8 KB)
    __shared__ float es[EMBED][CHUNK];   // E chunk: es[i][j]             (32 KB, reused as scratch later)
    __shared__ float rowm1[BR];
    __shared__ int   rowidx[BR];
    __shared__ float rowsq[BR];
    __shared__ int   flags[BR];

    const int t  = threadIdx.x;
    const int tj = t & 31;    // code-quad index: codes 4*tj .. 4*tj+3 of chunk
    const int tr = t >> 5;    // row-quad index: rows 4*tr .. 4*tr+3
    const int row0 = blockIdx.x * BR;

    // ---- stage X tile (transposed into LDS) ----
    {
        int r = t >> 3, i0 = (t & 7) * 8;
        const float* src = X + (size_t)(row0 + r) * EMBED + i0;
        float4 a = *(const float4*)(src);
        float4 b = *(const float4*)(src + 4);
        xs[i0 + 0][r] = a.x; xs[i0 + 1][r] = a.y; xs[i0 + 2][r] = a.z; xs[i0 + 3][r] = a.w;
        xs[i0 + 4][r] = b.x; xs[i0 + 5][r] = b.y; xs[i0 + 6][r] = b.z; xs[i0 + 7][r] = b.w;
    }
    __syncthreads();

    // ---- per-row ||x||^2 (for the loss only; precision not critical) ----
    if (t < BR) {
        float s = 0.f;
#pragma unroll
        for (int i = 0; i < EMBED; ++i) { float v = xs[i][t]; s = fmaf(v, v, s); }
        rowsq[t] = s;
    }

    // ---- main: score = c_j - 2 * x.e_j, track top-2 per row ----
    float m1[4] = {FLT_MAX, FLT_MAX, FLT_MAX, FLT_MAX};
    float m2[4] = {FLT_MAX, FLT_MAX, FLT_MAX, FLT_MAX};
    int   i1[4] = {0, 0, 0, 0};

    for (int ch = 0; ch < NCHUNK; ++ch) {
        __syncthreads();
        {   // stage E chunk: 64 x 128 floats, coalesced float4 loads
            int q = t & 31, ih = t >> 5;
#pragma unroll
            for (int k = 0; k < 8; ++k) {
                int i = ih + 8 * k;
                float4 v = *(const float4*)(E + (size_t)i * CODES + ch * CHUNK + q * 4);
                *(float4*)&es[i][q * 4] = v;
            }
        }
        __syncthreads();

        float acc[4][4];
#pragma unroll
        for (int r = 0; r < 4; ++r)
#pragma unroll
            for (int k = 0; k < 4; ++k) acc[r][k] = 0.f;

#pragma unroll 16
        for (int i = 0; i < EMBED; ++i) {
            float4 xv = *(const float4*)&xs[i][tr * 4];
            float4 ev = *(const float4*)&es[i][tj * 4];
            acc[0][0] = fmaf(xv.x, ev.x, acc[0][0]);
            acc[0][1] = fmaf(xv.x, ev.y, acc[0][1]);
            acc[0][2] = fmaf(xv.x, ev.z, acc[0][2]);
            acc[0][3] = fmaf(xv.x, ev.w, acc[0][3]);
            acc[1][0] = fmaf(xv.y, ev.x, acc[1][0]);
            acc[1][1] = fmaf(xv.y, ev.y, acc[1][1]);
            acc[1][2] = fmaf(xv.y, ev.z, acc[1][2]);
            acc[1][3] = fmaf(xv.y, ev.w, acc[1][3]);
            acc[2][0] = fmaf(xv.z, ev.x, acc[2][0]);
            acc[2][1] = fmaf(xv.z, ev.y, acc[2][1]);
            acc[2][2] = fmaf(xv.z, ev.z, acc[2][2]);
            acc[2][3] = fmaf(xv.z, ev.w, acc[2][3]);
            acc[3][0] = fmaf(xv.w, ev.x, acc[3][0]);
            acc[3][1] = fmaf(xv.w, ev.y, acc[3][1]);
            acc[3][2] = fmaf(xv.w, ev.z, acc[3][2]);
            acc[3][3] = fmaf(xv.w, ev.w, acc[3][3]);
        }

        float4 cv = *(const float4*)(cbuf + ch * CHUNK + tj * 4);
        float cc[4] = {cv.x, cv.y, cv.z, cv.w};
        int jbase = ch * CHUNK + tj * 4;
#pragma unroll
        for (int r = 0; r < 4; ++r) {
#pragma unroll
            for (int k = 0; k < 4; ++k) {
                float sc = fmaf(-2.f, acc[r][k], cc[k]);
                if (sc < m1[r]) { m2[r] = m1[r]; m1[r] = sc; i1[r] = jbase + k; }
                else if (sc < m2[r]) m2[r] = sc;
            }
        }
    }
    __syncthreads();  // es free from here on -> reuse as reduction scratch

    float*  m1s  = (float*)&es[0][0];            // [BR][33] = 4224 B
    float*  m2s  = m1s + BR * 33;                // 4224..8448
    int*    i1s  = (int*)(m2s + BR * 33);        // 8448..12672
    float*  fredv = (float*)((char*)&es[0][0] + 12672);   // 256 floats
    int*    fredi = (int*)((char*)&es[0][0] + 12672 + 1024); // 256 ints

#pragma unroll
    for (int rr = 0; rr < 4; ++rr) {
        int r = tr * 4 + rr;
        m1s[r * 33 + tj] = m1[rr];
        m2s[r * 33 + tj] = m2[rr];
        i1s[r * 33 + tj] = i1[rr];
    }
    __syncthreads();

    if (t < BR) {
        float M1 = FLT_MAX, M2 = FLT_MAX; int I1 = 0;
        for (int c = 0; c < 32; ++c) {
            float a = m1s[t * 33 + c];
            float b = m2s[t * 33 + c];
            int  ia = i1s[t * 33 + c];
            if (a < M1) { M2 = fminf(M1, b); M1 = a; I1 = ia; }
            else        { M2 = fminf(M2, a); }
        }
        rowm1[t]  = M1;
        rowidx[t] = I1;
        // near-tie -> re-decide by bit-exact fp32 numpy-reference emulation.
        // Ref decision noise is ~1.6e-5 (ulp(64)*2 + matmul noise); 2e-4 = 12x margin.
        flags[t]  = (M2 - M1 < 2e-4f) ? 1 : 0;
    }
    __syncthreads();

    // ---- rare fallback: bit-exact emulation of the fp32 numpy reference ----
    // d_j = fl( fl(A - fl(2*m_j)) + C_j ), A = np-pairwise sum of x*x,
    // m_j = sequential-FMA dot (OpenBLAS/Eigen k-loop), C_j from vq_precompute.
    // argmax(-d) = first occurrence of min d -> lexicographic (d, j) min.
    for (int r = 0; r < BR; ++r) {
        if (flags[r] == 0) continue;

        // A: numpy pairwise sum, n=64 path: 8 accumulators + tree combine (uniform).
        float racc[8];
#pragma unroll
        for (int jq = 0; jq < 8; ++jq) racc[jq] = __fmul_rn(xs[jq][r], xs[jq][r]);
#pragma unroll
        for (int i = 8; i < 64; i += 8)
#pragma unroll
            for (int jq = 0; jq < 8; ++jq)
                racc[jq] = __fadd_rn(racc[jq], __fmul_rn(xs[i + jq][r], xs[i + jq][r]));
        float A = __fadd_rn(
            __fadd_rn(__fadd_rn(racc[0], racc[1]), __fadd_rn(racc[2], racc[3])),
            __fadd_rn(__fadd_rn(racc[4], racc[5]), __fadd_rn(racc[6], racc[7])));

        float best = FLT_MAX; int bestj = CODES;
#pragma unroll 1
        for (int jj = 0; jj < 16; ++jj) {
            int j = jj * 256 + t;           // ascending j within thread
            float m = 0.f;
#pragma unroll
            for (int i = 0; i < 64; ++i)
                m = fmaf(xs[i][r], E[(size_t)i * CODES + j], m);  // sequential FMA chain
            float d = __fadd_rn(__fsub_rn(A, __fmul_rn(2.f, m)), cbuf[j]);
            if (d < best || (d == best && j < bestj)) { best = d; bestj = j; }
        }
        fredv[t] = best; fredi[t] = bestj;
        __syncthreads();
        if (t == 0) {
            float B = fredv[0]; int BI = fredi[0];
            for (int c = 1; c < 256; ++c) {
                float dc = fredv[c]; int jc = fredi[c];
                if (dc < B || (dc == B && jc < BI)) { B = dc; BI = jc; }
            }
            rowidx[r] = BI;
        }
        __syncthreads();
    }

    // ---- outputs ----
    if (t < BR) {
        out[(size_t)NELEM + 1 + row0 + t] = (float)rowidx[t];  // idx written as float
    }
    if (t == 0) {
        float bs = 0.f;
        for (int r = 0; r < BR; ++r) bs += rowsq[r] + rowm1[r];  // sum (x-e)^2 for block
        atomicAdd(accum, (double)bs);
    }
    {
        int r = t >> 3, i0 = (t & 7) * 8;
        int j = rowidx[r];
        float o[8];
#pragma unroll
        for (int k = 0; k < 8; ++k) o[k] = E[(size_t)(i0 + k) * CODES + j];
        float* dst = out + (size_t)(row0 + r) * EMBED + i0;
        *(float4*)(dst)     = make_float4(o[0], o[1], o[2], o[3]);
        *(float4*)(dst + 4) = make_float4(o[4], o[5], o[6], o[7]);
    }
}

__global__ void vq_finalize(const double* __restrict__ accum, float* __restrict__ out) {
    out[NELEM] = (float)(0.25 * (*accum) / (double)NELEM);
}

extern "C" void kernel_launch(void* const* d_in, const int* in_sizes, int n_in,
                              void* d_out, int out_size, void* d_ws, size_t ws_size,
                              hipStream_t stream) {
    const float* X = (const float*)d_in[0];   // (512, 8192, 1) f32 -> 65536 rows x 64
    const float* E = (const float*)d_in[1];   // (64, 4096) f32 row-major
    float* out = (float*)d_out;
    float* cbuf = (float*)d_ws;
    double* accum = (double*)((char*)d_ws + CODES * sizeof(float));

    vq_precompute<<<CODES / 256, 256, 0, stream>>>(E, cbuf, accum);
    vq_main<<<NROWS / BR, 256, 0, stream>>>(X, E, cbuf, accum, out);
    vq_finalize<<<1, 1, 0, stream>>>(accum, out);
}

// Round 3
// 424.118 us; speedup vs baseline: 1.5816x; 1.5816x over previous
//
#include <hip/hip_runtime.h>
#include <float.h>

#define EMBED   64
#define CODES   4096
#define NROWS   65536      // 512*8192/64
#define NELEM   4194304    // 512*8192
#define BR      128        // rows per block (4 waves x 32 rows)
#define CCH     128        // codes staged per chunk (4 tiles of 32)
#define NCH     (CODES / CCH)

typedef __attribute__((ext_vector_type(8)))  short bf16x8;   // 8 bf16 in 4 VGPRs
typedef __attribute__((ext_vector_type(16))) float f32x16;   // MFMA 32x32 accumulator

__device__ inline unsigned short f2bf(float f) {             // RNE float->bf16
    unsigned u = __float_as_uint(f);
    u += 0x7fff + ((u >> 16) & 1);
    return (unsigned short)(u >> 16);
}
__device__ inline float bf2f(unsigned short h) {
    return __uint_as_float(((unsigned)h) << 16);
}

// ws: [0..CODES) float c_j = ||e_j||^2 (np-fp32-emulated), then one double loss accum
__global__ void vq_precompute(const float* __restrict__ E, float* __restrict__ cbuf,
                              double* __restrict__ accum) {
    int j = blockIdx.x * 256 + threadIdx.x;
    // Emulate np.sum(E*E, axis=0) C-order: sequential over i, separate mul/add rounding.
    float v = E[j];
    float s = __fmul_rn(v, v);
    for (int i = 1; i < EMBED; ++i) {
        v = E[(size_t)i * CODES + j];
        s = __fadd_rn(s, __fmul_rn(v, v));
    }
    cbuf[j] = s;
    if (j == 0) *accum = 0.0;   // d_ws poisoned 0xAA before every launch
}

__global__ __launch_bounds__(256)
void vq_main(const float* __restrict__ X, const float* __restrict__ E,
             const float* __restrict__ cbuf, double* __restrict__ accum,
             float* __restrict__ out) {
    // B-fragment chunk buffer: [tile(4)][kstep(4)][split(2)][lane(64)] x 16B = 32 KB
    __shared__ bf16x8 lbuf[2048];
    __shared__ float rowm1[BR], rowsq[BR];
    __shared__ int   rowidx[BR], rowflag[BR];
    __shared__ float fredv[256];
    __shared__ int   fredi[256];

    const int t  = threadIdx.x;
    const int l  = t & 63, wv = t >> 6;
    const int m  = l & 31, h  = l >> 5;     // MFMA row-lane / k-half
    const int row0 = blockIdx.x * BR;

    // ---- A fragments (persistent in regs): x split hi/lo, plus ||x||^2 ----
    bf16x8 ah[4], al[4];
    {
        const float* xrow = X + (size_t)(row0 + wv * 32 + m) * EMBED;
        float sq = 0.f;
#pragma unroll
        for (int kk = 0; kk < 4; ++kk) {
            int kb = kk * 16 + h * 8;
            float4 v0 = *(const float4*)(xrow + kb);
            float4 v1 = *(const float4*)(xrow + kb + 4);
            float xv[8] = {v0.x, v0.y, v0.z, v0.w, v1.x, v1.y, v1.z, v1.w};
#pragma unroll
            for (int j = 0; j < 8; ++j) {
                sq = fmaf(xv[j], xv[j], sq);
                unsigned short hi = f2bf(xv[j]);
                float r = xv[j] - bf2f(hi);
                ah[kk][j] = (short)hi;
                al[kk][j] = (short)f2bf(r);
            }
        }
        sq += __shfl_xor(sq, 32, 64);       // lanes l and l+32 hold same row
        if (h == 0) rowsq[wv * 32 + m] = sq;
    }

    // top-2 (max of acc = m - c/2  <=>  min of score = c - 2m) per C-reg slot
    float M1[16], M2[16]; int I1[16];
#pragma unroll
    for (int e = 0; e < 16; ++e) { M1[e] = -FLT_MAX; M2[e] = -FLT_MAX; I1[e] = 0; }

    for (int ch = 0; ch < NCH; ++ch) {
        __syncthreads();
        // ---- stage+split E chunk into B-fragment layout in LDS ----
#pragma unroll
        for (int q = 0; q < 4; ++q) {
            int unit = q * 256 + t;              // [tl(4)][kk(4)][lam(64)]
            int lam = unit & 63;
            int kk  = (unit >> 6) & 3;
            int tl  = unit >> 8;
            int n = ch * CCH + tl * 32 + (lam & 31);
            const float* ecol = E + (size_t)(kk * 16 + (lam >> 5) * 8) * CODES + n;
            bf16x8 vh, vl;
#pragma unroll
            for (int j = 0; j < 8; ++j) {
                float e = ecol[(size_t)j * CODES];
                unsigned short hi = f2bf(e);
                float r = e - bf2f(hi);
                vh[j] = (short)hi;
                vl[j] = (short)f2bf(r);
            }
            lbuf[((tl * 4 + kk) * 2 + 0) * 64 + lam] = vh;
            lbuf[((tl * 4 + kk) * 2 + 1) * 64 + lam] = vl;
        }
        __syncthreads();

#pragma unroll 1
        for (int tl = 0; tl < 4; ++tl) {
            int tile = ch * 4 + tl;
            float cj = cbuf[tile * 32 + m];      // per-lane code constant (col = lane&31)
            f32x16 acc;
#pragma unroll
            for (int e = 0; e < 16; ++e) acc[e] = -0.5f * cj;
#pragma unroll
            for (int kk = 0; kk < 4; ++kk) {
                bf16x8 bh = lbuf[((tl * 4 + kk) * 2 + 0) * 64 + l];
                bf16x8 bl = lbuf[((tl * 4 + kk) * 2 + 1) * 64 + l];
                acc = __builtin_amdgcn_mfma_f32_32x32x16_bf16(ah[kk], bh, acc, 0, 0, 0);
                acc = __builtin_amdgcn_mfma_f32_32x32x16_bf16(ah[kk], bl, acc, 0, 0, 0);
                acc = __builtin_amdgcn_mfma_f32_32x32x16_bf16(al[kk], bh, acc, 0, 0, 0);
            }
            int j = tile * 32 + m;               // same code for all 16 regs of this lane
#pragma unroll
            for (int e = 0; e < 16; ++e) {
                float a = acc[e];
                bool c = a > M1[e];
                M2[e] = c ? M1[e] : fmaxf(M2[e], a);
                I1[e] = c ? j : I1[e];
                M1[e] = fmaxf(M1[e], a);
            }
        }
    }

    // ---- cross-lane top-2 merge within each 32-lane half ----
#pragma unroll
    for (int d = 1; d < 32; d <<= 1) {
#pragma unroll
        for (int e = 0; e < 16; ++e) {
            float oM1 = __shfl_xor(M1[e], d, 64);
            float oM2 = __shfl_xor(M2[e], d, 64);
            int   oI  = __shfl_xor(I1[e], d, 64);
            float lo  = fminf(M1[e], oM1);
            M2[e] = fmaxf(lo, fmaxf(M2[e], oM2));
            bool c = oM1 > M1[e];
            I1[e] = c ? oI : I1[e];
            M1[e] = c ? oM1 : M1[e];
        }
    }
    // C/D row = (reg&3) + 8*(reg>>2) + 4*(lane>>5); one lane writes each row
#pragma unroll
    for (int e = 0; e < 16; ++e) {
        int r = (e & 3) + 8 * (e >> 2) + 4 * h;
        if (m == r) {
            rowm1[wv * 32 + r]  = M1[e];
            rowidx[wv * 32 + r] = I1[e];
            rowflag[wv * 32 + r] = (2.f * (M1[e] - M2[e]) < 2e-4f) ? 1 : 0;
        }
    }
    __syncthreads();

    // ---- rare fallback: bit-exact fp32 numpy-reference emulation (uniform branch) ----
#pragma unroll 1
    for (int r = 0; r < BR; ++r) {
        if (rowflag[r] == 0) continue;
        const float* xr = X + (size_t)(row0 + r) * EMBED;
        // A: numpy pairwise sum of x*x (n=64: 8 accumulators + tree combine)
        float racc[8];
#pragma unroll
        for (int jq = 0; jq < 8; ++jq) racc[jq] = __fmul_rn(xr[jq], xr[jq]);
#pragma unroll
        for (int i = 8; i < 64; i += 8)
#pragma unroll
            for (int jq = 0; jq < 8; ++jq)
                racc[jq] = __fadd_rn(racc[jq], __fmul_rn(xr[i + jq], xr[i + jq]));
        float A = __fadd_rn(
            __fadd_rn(__fadd_rn(racc[0], racc[1]), __fadd_rn(racc[2], racc[3])),
            __fadd_rn(__fadd_rn(racc[4], racc[5]), __fadd_rn(racc[6], racc[7])));

        float best = FLT_MAX; int bestj = CODES;
#pragma unroll 1
        for (int jj = 0; jj < 16; ++jj) {
            int j = jj * 256 + t;
            float mm = 0.f;
#pragma unroll
            for (int i = 0; i < 64; ++i)
                mm = fmaf(xr[i], E[(size_t)i * CODES + j], mm);  // sequential FMA (BLAS k-loop)
            float d = __fadd_rn(__fsub_rn(A, __fmul_rn(2.f, mm)), cbuf[j]);
            if (d < best || (d == best && j < bestj)) { best = d; bestj = j; }
        }
        fredv[t] = best; fredi[t] = bestj;
        __syncthreads();
        if (t == 0) {
            float B = fredv[0]; int BI = fredi[0];
            for (int c2 = 1; c2 < 256; ++c2) {
                float dc = fredv[c2]; int jc = fredi[c2];
                if (dc < B || (dc == B && jc < BI)) { B = dc; BI = jc; }
            }
            rowidx[r] = BI;
        }
        __syncthreads();
    }

    // ---- outputs ----
    if (t < BR) out[(size_t)NELEM + 1 + row0 + t] = (float)rowidx[t];  // idx as float
    if (t == 0) {
        float bs = 0.f;
        for (int r = 0; r < BR; ++r) bs += rowsq[r] - 2.f * rowm1[r];  // sum (x-e)^2
        atomicAdd(accum, (double)bs);
    }
    {
        int r = t >> 1, i0 = (t & 1) * 32;
        int j = rowidx[r];
        float* dst = out + (size_t)(row0 + r) * EMBED + i0;
#pragma unroll
        for (int g = 0; g < 8; ++g) {
            float4 v;
            v.x = E[(size_t)(i0 + g * 4 + 0) * CODES + j];
            v.y = E[(size_t)(i0 + g * 4 + 1) * CODES + j];
            v.z = E[(size_t)(i0 + g * 4 + 2) * CODES + j];
            v.w = E[(size_t)(i0 + g * 4 + 3) * CODES + j];
            *(float4*)(dst + g * 4) = v;
        }
    }
}

__global__ void vq_finalize(const double* __restrict__ accum, float* __restrict__ out) {
    out[NELEM] = (float)(0.25 * (*accum) / (double)NELEM);
}

extern "C" void kernel_launch(void* const* d_in, const int* in_sizes, int n_in,
                              void* d_out, int out_size, void* d_ws, size_t ws_size,
                              hipStream_t stream) {
    const float* X = (const float*)d_in[0];   // (512, 8192, 1) f32 -> 65536 rows x 64
    const float* E = (const float*)d_in[1];   // (64, 4096) f32 row-major
    float* out = (float*)d_out;
    float* cbuf = (float*)d_ws;
    double* accum = (double*)((char*)d_ws + CODES * sizeof(float));

    vq_precompute<<<CODES / 256, 256, 0, stream>>>(E, cbuf, accum);
    vq_main<<<NROWS / BR, 256, 0, stream>>>(X, E, cbuf, accum, out);
    vq_finalize<<<1, 1, 0, stream>>>(accum, out);
}

// Round 4
// 279.826 us; speedup vs baseline: 2.3971x; 1.5156x over previous
//
#include <hip/hip_runtime.h>
#include <float.h>

#define EMBED   64
#define CODES   4096
#define NROWS   65536      // 512*8192/64
#define NELEM   4194304    // 512*8192
#define BR      128        // rows per block (4 waves x 32 rows)
#define CCH     128        // codes staged per chunk (4 tiles of 32)
#define NCH     (CODES / CCH)
#define CUNITS  2048       // 16B fragment units per chunk (4 tiles * 512)

typedef __attribute__((ext_vector_type(8)))  short bf16x8;   // 8 bf16 in 4 VGPRs
typedef __attribute__((ext_vector_type(16))) float f32x16;   // MFMA 32x32 accumulator

__device__ inline unsigned short f2bf(float f) {             // RNE float->bf16
    unsigned u = __float_as_uint(f);
    u += 0x7fff + ((u >> 16) & 1);
    return (unsigned short)(u >> 16);
}
__device__ inline float bf2f(unsigned short h) {
    return __uint_as_float(((unsigned)h) << 16);
}

// ws layout: [0,16K) cbuf (||e_j||^2, np-fp32-emulated); [16K] double accum;
//            [32K, 32K+1M) packed B-fragments (bf16 hi/lo); then 1M ET (E^T fp32)
__global__ void vq_precompute(const float* __restrict__ E, float* __restrict__ cbuf,
                              double* __restrict__ accum) {
    int j = blockIdx.x * 256 + threadIdx.x;
    float v = E[j];
    float s = __fmul_rn(v, v);
    for (int i = 1; i < EMBED; ++i) {
        v = E[(size_t)i * CODES + j];
        s = __fadd_rn(s, __fmul_rn(v, v));
    }
    cbuf[j] = s;
    if (j == 0) *accum = 0.0;   // d_ws poisoned 0xAA before every launch
}

// pack E into MFMA B-fragment order: unit u = ((g*4+kk)*2+sp)*64+lam,
// lane lam holds codes n=g*32+(lam&31), k = kk*16+(lam>>5)*8 + [0..8)
__global__ void vq_prepack(const float* __restrict__ E, bf16x8* __restrict__ packed) {
    int u = blockIdx.x * 256 + threadIdx.x;   // 65536 units
    int lam = u & 63, sp = (u >> 6) & 1, kk = (u >> 7) & 3, g = u >> 9;
    int n  = g * 32 + (lam & 31);
    int kb = kk * 16 + (lam >> 5) * 8;
    bf16x8 v;
#pragma unroll
    for (int j = 0; j < 8; ++j) {
        float e = E[(size_t)(kb + j) * CODES + n];
        unsigned short hi = f2bf(e);
        v[j] = sp ? (short)f2bf(e - bf2f(hi)) : (short)hi;
    }
    packed[u] = v;
}

__global__ void vq_prepack_et(const float* __restrict__ E, float* __restrict__ ET) {
    int id = blockIdx.x * 256 + threadIdx.x;  // 65536 quads
    int j = id >> 4, i0 = (id & 15) * 4;
    float4 v;
    v.x = E[(size_t)(i0 + 0) * CODES + j];
    v.y = E[(size_t)(i0 + 1) * CODES + j];
    v.z = E[(size_t)(i0 + 2) * CODES + j];
    v.w = E[(size_t)(i0 + 3) * CODES + j];
    *(float4*)(ET + (size_t)j * EMBED + i0) = v;
}

template <bool PRE>
__global__ __launch_bounds__(256, 2)
void vq_main(const float* __restrict__ X, const float* __restrict__ E,
             const float* __restrict__ cbuf, const bf16x8* __restrict__ packed,
             const float* __restrict__ ET, double* __restrict__ accum,
             float* __restrict__ out) {
    __shared__ bf16x8 lbuf[2][CUNITS];        // 64 KB exactly; scratch overlays after loop

    const int t  = threadIdx.x;
    const int l  = t & 63, wv = t >> 6;
    const int m  = l & 31, h  = l >> 5;
    const int row0 = blockIdx.x * BR;

    // ---- A fragments (persistent): x split hi/lo; row ||x||^2 kept in reg ----
    bf16x8 ah[4], al[4];
    float sqreg;
    {
        const float* xrow = X + (size_t)(row0 + wv * 32 + m) * EMBED;
        float sq = 0.f;
#pragma unroll
        for (int kk = 0; kk < 4; ++kk) {
            int kb = kk * 16 + h * 8;
            float4 v0 = *(const float4*)(xrow + kb);
            float4 v1 = *(const float4*)(xrow + kb + 4);
            float xv[8] = {v0.x, v0.y, v0.z, v0.w, v1.x, v1.y, v1.z, v1.w};
#pragma unroll
            for (int j = 0; j < 8; ++j) {
                sq = fmaf(xv[j], xv[j], sq);
                unsigned short hi = f2bf(xv[j]);
                float r = xv[j] - bf2f(hi);
                ah[kk][j] = (short)hi;
                al[kk][j] = (short)f2bf(r);
            }
        }
        sq += __shfl_xor(sq, 32, 64);          // lanes l and l+32 hold same row
        sqreg = sq;
    }

    auto stage = [&](int ch, int buf) {
        if constexpr (PRE) {
#pragma unroll
            for (int q = 0; q < 8; ++q) {
                const bf16x8* gp = packed + (size_t)ch * CUNITS + q * 256 + t;
                bf16x8* lp = &lbuf[buf][q * 256 + wv * 64];  // wave-uniform base, +lane*16 implicit
                __builtin_amdgcn_global_load_lds(
                    (const __attribute__((address_space(1))) void*)gp,
                    (__attribute__((address_space(3))) void*)lp, 16, 0, 0);
            }
        } else {
#pragma unroll
            for (int q = 0; q < 4; ++q) {
                int unit = q * 256 + t;
                int lam = unit & 63, kk = (unit >> 6) & 3, tl = unit >> 8;
                int n = ch * CCH + tl * 32 + (lam & 31);
                const float* ecol = E + (size_t)(kk * 16 + (lam >> 5) * 8) * CODES + n;
                bf16x8 vh, vl;
#pragma unroll
                for (int j = 0; j < 8; ++j) {
                    float e = ecol[(size_t)j * CODES];
                    unsigned short hi = f2bf(e);
                    vh[j] = (short)hi;
                    vl[j] = (short)f2bf(e - bf2f(hi));
                }
                lbuf[buf][tl * 512 + kk * 128 + lam]      = vh;
                lbuf[buf][tl * 512 + kk * 128 + 64 + lam] = vl;
            }
        }
    };

    // top-2 (max of a = x.e - c/2  <=>  min score) per C-reg slot
    float M1[16], M2[16]; int I1[16];
#pragma unroll
    for (int e = 0; e < 16; ++e) { M1[e] = -FLT_MAX; M2[e] = -FLT_MAX; I1[e] = 0; }

    stage(0, 0);
    __syncthreads();

    int b = 0;
    for (int ch = 0; ch < NCH; ++ch) {
        if (ch + 1 < NCH) stage(ch + 1, b ^ 1);

        const bf16x8* lb = lbuf[b];
        float nc[4];
#pragma unroll
        for (int tl = 0; tl < 4; ++tl) nc[tl] = -0.5f * cbuf[(ch * 4 + tl) * 32 + m];

#pragma unroll
        for (int pp = 0; pp < 2; ++pp) {
            const int tl0 = pp * 2, tl1 = tl0 + 1;
            bf16x8 B0[8], B1[8];                 // [kk*2 + split]
#pragma unroll
            for (int kk = 0; kk < 4; ++kk) {
                B0[kk * 2]     = lb[tl0 * 512 + kk * 128 + l];
                B0[kk * 2 + 1] = lb[tl0 * 512 + kk * 128 + 64 + l];
                B1[kk * 2]     = lb[tl1 * 512 + kk * 128 + l];
                B1[kk * 2 + 1] = lb[tl1 * 512 + kk * 128 + 64 + l];
            }
            f32x16 a0, a1;
#pragma unroll
            for (int e = 0; e < 16; ++e) { a0[e] = nc[tl0]; a1[e] = nc[tl1]; }
#pragma unroll
            for (int kk = 0; kk < 4; ++kk) {     // two independent acc chains
                a0 = __builtin_amdgcn_mfma_f32_32x32x16_bf16(ah[kk], B0[kk * 2],     a0, 0, 0, 0);
                a1 = __builtin_amdgcn_mfma_f32_32x32x16_bf16(ah[kk], B1[kk * 2],     a1, 0, 0, 0);
                a0 = __builtin_amdgcn_mfma_f32_32x32x16_bf16(ah[kk], B0[kk * 2 + 1], a0, 0, 0, 0);
                a1 = __builtin_amdgcn_mfma_f32_32x32x16_bf16(ah[kk], B1[kk * 2 + 1], a1, 0, 0, 0);
                a0 = __builtin_amdgcn_mfma_f32_32x32x16_bf16(al[kk], B0[kk * 2],     a0, 0, 0, 0);
                a1 = __builtin_amdgcn_mfma_f32_32x32x16_bf16(al[kk], B1[kk * 2],     a1, 0, 0, 0);
            }
            int j0 = (ch * 4 + tl0) * 32 + m, j1 = (ch * 4 + tl1) * 32 + m;
#pragma unroll
            for (int e = 0; e < 16; ++e) {
                { float a = a0[e]; bool c = a > M1[e];
                  M2[e] = c ? M1[e] : fmaxf(M2[e], a);
                  I1[e] = c ? j0 : I1[e];
                  M1[e] = fmaxf(M1[e], a); }
                { float a = a1[e]; bool c = a > M1[e];
                  M2[e] = c ? M1[e] : fmaxf(M2[e], a);
                  I1[e] = c ? j1 : I1[e];
                  M1[e] = fmaxf(M1[e], a); }
            }
        }
        __syncthreads();
        b ^= 1;
    }
    // all waves past final barrier -> lbuf dead; overlay scratch
    float* rowm1  = (float*)&lbuf[0][0];
    float* rowsq  = rowm1 + BR;
    int*   rowidx = (int*)(rowsq + BR);
    int*   rowflg = rowidx + BR;
    float* fredv  = (float*)(rowflg + BR);
    int*   fredi  = (int*)(fredv + 256);

    // ---- cross-lane top-2 merge within each 32-lane half ----
#pragma unroll
    for (int d = 1; d < 32; d <<= 1) {
#pragma unroll
        for (int e = 0; e < 16; ++e) {
            float oM1 = __shfl_xor(M1[e], d, 64);
            float oM2 = __shfl_xor(M2[e], d, 64);
            int   oI  = __shfl_xor(I1[e], d, 64);
            float lo  = fminf(M1[e], oM1);
            M2[e] = fmaxf(lo, fmaxf(M2[e], oM2));
            bool c = oM1 > M1[e];
            I1[e] = c ? oI : I1[e];
            M1[e] = c ? oM1 : M1[e];
        }
    }
    if (h == 0) rowsq[wv * 32 + m] = sqreg;
    // C/D row = (reg&3) + 8*(reg>>2) + 4*(lane>>5); one lane writes each row
#pragma unroll
    for (int e = 0; e < 16; ++e) {
        int r = (e & 3) + 8 * (e >> 2) + 4 * h;
        if (m == r) {
            rowm1[wv * 32 + r]  = M1[e];
            rowidx[wv * 32 + r] = I1[e];
            rowflg[wv * 32 + r] = (2.f * (M1[e] - M2[e]) < 2e-4f) ? 1 : 0;
        }
    }
    __syncthreads();

    // ---- rare fallback: bit-exact fp32 numpy-reference emulation (uniform branch) ----
#pragma unroll 1
    for (int r = 0; r < BR; ++r) {
        if (rowflg[r] == 0) continue;
        const float* xr = X + (size_t)(row0 + r) * EMBED;
        float racc[8];
#pragma unroll
        for (int jq = 0; jq < 8; ++jq) racc[jq] = __fmul_rn(xr[jq], xr[jq]);
#pragma unroll
        for (int i = 8; i < 64; i += 8)
#pragma unroll
            for (int jq = 0; jq < 8; ++jq)
                racc[jq] = __fadd_rn(racc[jq], __fmul_rn(xr[i + jq], xr[i + jq]));
        float A = __fadd_rn(
            __fadd_rn(__fadd_rn(racc[0], racc[1]), __fadd_rn(racc[2], racc[3])),
            __fadd_rn(__fadd_rn(racc[4], racc[5]), __fadd_rn(racc[6], racc[7])));

        float best = FLT_MAX; int bestj = CODES;
#pragma unroll 1
        for (int jj = 0; jj < 16; ++jj) {
            int j = jj * 256 + t;
            float mm = 0.f;
#pragma unroll
            for (int i = 0; i < 64; ++i)
                mm = fmaf(xr[i], E[(size_t)i * CODES + j], mm);  // sequential FMA (BLAS k-loop)
            float d = __fadd_rn(__fsub_rn(A, __fmul_rn(2.f, mm)), cbuf[j]);
            if (d < best || (d == best && j < bestj)) { best = d; bestj = j; }
        }
        fredv[t] = best; fredi[t] = bestj;
        __syncthreads();
        if (t == 0) {
            float B = fredv[0]; int BI = fredi[0];
            for (int c2 = 1; c2 < 256; ++c2) {
                float dc = fredv[c2]; int jc = fredi[c2];
                if (dc < B || (dc == B && jc < BI)) { B = dc; BI = jc; }
            }
            rowidx[r] = BI;
        }
        __syncthreads();
    }

    // ---- outputs ----
    if (t < BR) out[(size_t)NELEM + 1 + row0 + t] = (float)rowidx[t];  // idx as float
    if (t == 0) {
        float bs = 0.f;
        for (int r = 0; r < BR; ++r) bs += rowsq[r] - 2.f * rowm1[r];  // sum (x-e)^2
        atomicAdd(accum, (double)bs);
    }
    {
        int r = t >> 1, i0 = (t & 1) * 32;
        int j = rowidx[r];
        float* dst = out + (size_t)(row0 + r) * EMBED + i0;
        if constexpr (PRE) {
            const float* src = ET + (size_t)j * EMBED + i0;
#pragma unroll
            for (int g = 0; g < 8; ++g)
                *(float4*)(dst + g * 4) = *(const float4*)(src + g * 4);
        } else {
#pragma unroll
            for (int g = 0; g < 8; ++g) {
                float4 v;
                v.x = E[(size_t)(i0 + g * 4 + 0) * CODES + j];
                v.y = E[(size_t)(i0 + g * 4 + 1) * CODES + j];
                v.z = E[(size_t)(i0 + g * 4 + 2) * CODES + j];
                v.w = E[(size_t)(i0 + g * 4 + 3) * CODES + j];
                *(float4*)(dst + g * 4) = v;
            }
        }
    }
}

__global__ void vq_finalize(const double* __restrict__ accum, float* __restrict__ out) {
    out[NELEM] = (float)(0.25 * (*accum) / (double)NELEM);
}

extern "C" void kernel_launch(void* const* d_in, const int* in_sizes, int n_in,
                              void* d_out, int out_size, void* d_ws, size_t ws_size,
                              hipStream_t stream) {
    const float* X = (const float*)d_in[0];   // (512, 8192, 1) f32 -> 65536 rows x 64
    const float* E = (const float*)d_in[1];   // (64, 4096) f32 row-major
    float* out = (float*)d_out;
    float*  cbuf   = (float*)d_ws;
    double* accum  = (double*)((char*)d_ws + 16384);
    bf16x8* packed = (bf16x8*)((char*)d_ws + 32768);
    float*  ET     = (float*)((char*)d_ws + 32768 + 1048576);
    const size_t need = 32768 + 1048576 + 1048576;
    const bool pre = (ws_size >= need);       // constant across calls -> same work every call

    vq_precompute<<<CODES / 256, 256, 0, stream>>>(E, cbuf, accum);
    if (pre) {
        vq_prepack<<<256, 256, 0, stream>>>(E, packed);
        vq_prepack_et<<<256, 256, 0, stream>>>(E, ET);
        vq_main<true><<<NROWS / BR, 256, 0, stream>>>(X, E, cbuf, packed, ET, accum, out);
    } else {
        vq_main<false><<<NROWS / BR, 256, 0, stream>>>(X, E, cbuf, packed, ET, accum, out);
    }
    vq_finalize<<<1, 1, 0, stream>>>(accum, out);
}